// Round 1
// 505.919 us; speedup vs baseline: 1.0482x; 1.0482x over previous
//
#include <hip/hip_runtime.h>

// Bilinear resample with zero-padding OOB semantics (tf resampler behavior).
// imgs: (B,H,W,1) f32, dvfs: (B,H,W,2) f32 (ch0 = x offset, ch1 = y offset)
// out:  (B,H,W,1) f32.  B=32, H=W=1024 for this problem instance.
//
// Layout change vs prev version: ONE pixel per lane (unit-stride lanes) instead
// of 4 consecutive pixels per lane. The 4 corner gathers then have consecutive
// lanes at consecutive x (only dy-row scatter remains), cutting distinct
// cache-lines-per-gather-instruction from ~64 to ~16 and letting v01/v11 hit
// the lines fetched by v00/v10 in L1. dvfs load is a coalesced dwordx2/lane.
// dvfs/out are stream-once -> nontemporal, preserving L2 for imgs reuse.

#define H_DIM 1024
#define W_DIM 1024
#define HW_SHIFT 20            // H_DIM * W_DIM == 1 << 20
#define HW_PIX (1 << HW_SHIFT)

__device__ __forceinline__ float gather_zp(const float* __restrict__ img,
                                           int yy, int xx) {
    bool valid = (xx >= 0) & (xx < W_DIM) & (yy >= 0) & (yy < H_DIM);
    int xc = min(max(xx, 0), W_DIM - 1);
    int yc = min(max(yy, 0), H_DIM - 1);
    float v = img[yc * W_DIM + xc];
    return valid ? v : 0.0f;
}

__global__ __launch_bounds__(256) void bilerp_kernel(
        const float* __restrict__ imgs,
        const float* __restrict__ dvfs,
        float* __restrict__ out,
        int total_pixels) {
    int pix = blockIdx.x * 256 + threadIdx.x;
    if (pix >= total_pixels) return;

    int b   = pix >> HW_SHIFT;
    int rem = pix & (HW_PIX - 1);
    int y   = rem >> 10;            // W_DIM == 1024
    int x   = rem & (W_DIM - 1);

    const float* __restrict__ img = imgs + ((long long)b << HW_SHIFT);

    // (dx, dy) for this pixel: coalesced 8B/lane load, nontemporal (stream-once).
    union { double d64; float2 f2; } cvt;
    cvt.d64 = __builtin_nontemporal_load(
        reinterpret_cast<const double*>(dvfs) + pix);
    float dx = cvt.f2.x;
    float dy = cvt.f2.y;

    float fx = (float)x + dx;
    float fy = (float)y + dy;
    float x0f = floorf(fx);
    float y0f = floorf(fy);
    float wx = fx - x0f;
    float wy = fy - y0f;
    int x0 = (int)x0f;
    int y0 = (int)y0f;

    float v00 = gather_zp(img, y0,     x0);
    float v01 = gather_zp(img, y0,     x0 + 1);
    float v10 = gather_zp(img, y0 + 1, x0);
    float v11 = gather_zp(img, y0 + 1, x0 + 1);

    // Same expression shape as the reference (keep rounding behavior close).
    float res = v00 * (1.0f - wx) * (1.0f - wy)
              + v01 * wx          * (1.0f - wy)
              + v10 * (1.0f - wx) * wy
              + v11 * wx          * wy;

    __builtin_nontemporal_store(res, out + pix);
}

extern "C" void kernel_launch(void* const* d_in, const int* in_sizes, int n_in,
                              void* d_out, int out_size, void* d_ws, size_t ws_size,
                              hipStream_t stream) {
    const float* imgs = (const float*)d_in[0];
    const float* dvfs = (const float*)d_in[1];
    float* out = (float*)d_out;

    int total_pixels = out_size;  // B*H*W*1 elements
    int block = 256;
    int grid = (total_pixels + block - 1) / block;

    bilerp_kernel<<<grid, block, 0, stream>>>(imgs, dvfs, out, total_pixels);
}